// Round 9
// baseline (390.657 us; speedup 1.0000x reference)
//
#include <hip/hip_runtime.h>
#include <hip/hip_bf16.h>

#define B_   4
#define S_   1024
#define E_   1024
#define H_   16
#define HD_  64

typedef float  f32x4  __attribute__((ext_vector_type(4)));
typedef short  bf16x8 __attribute__((ext_vector_type(8)));
typedef short  bf16x4 __attribute__((ext_vector_type(4)));

__device__ __forceinline__ float bf2f(short u) {
  union { unsigned int i; float f; } v;
  v.i = ((unsigned int)(unsigned short)u) << 16;
  return v.f;
}
__device__ __forceinline__ short f2bf(float f) {
  unsigned int x = __float_as_uint(f);
  x = x + 0x7fffu + ((x >> 16) & 1u);   // RTNE
  return (short)(x >> 16);
}
__device__ __forceinline__ bf16x8 ld_cvt8(const float* __restrict__ p) {
  const f32x4 a = *(const f32x4*)p;
  const f32x4 b = *(const f32x4*)(p + 4);
  bf16x8 r;
  r[0] = f2bf(a[0]); r[1] = f2bf(a[1]); r[2] = f2bf(a[2]); r[3] = f2bf(a[3]);
  r[4] = f2bf(b[0]); r[5] = f2bf(b[1]); r[6] = f2bf(b[2]); r[7] = f2bf(b[3]);
  return r;
}

// async global->LDS, 16B per lane. LDS dest must be wave-uniform base + lane*16.
__device__ __forceinline__ void gload_lds16(const short* g, short* l) {
  __builtin_amdgcn_global_load_lds(
      (const __attribute__((address_space(1))) void*)g,
      (__attribute__((address_space(3))) void*)l, 16, 0, 0);
}

// ---------------------------------------------------------------------------
// fp32 -> bf16 bulk converts
// ---------------------------------------------------------------------------
__global__ __launch_bounds__(256) void cvt_f32_bf16(
    const float* __restrict__ src, short* __restrict__ dst, int n)
{
  const int i = (blockIdx.x * 256 + threadIdx.x) * 4;
  if (i < n) {
    const f32x4 v = *(const f32x4*)(src + i);
    bf16x4 o;
    o[0] = f2bf(v[0]); o[1] = f2bf(v[1]); o[2] = f2bf(v[2]); o[3] = f2bf(v[3]);
    *(bf16x4*)(dst + i) = o;
  }
}

// y=0..2: Wq/Wk/Wv -> WB ; y=3..6: x quarters -> xbf (in d_out scratch)
__global__ __launch_bounds__(256) void cvt7_f32_bf16(
    const float* __restrict__ w0, const float* __restrict__ w1,
    const float* __restrict__ w2, const float* __restrict__ x,
    short* __restrict__ WB, short* __restrict__ xbf)
{
  const int NW = E_ * E_;
  const int y = blockIdx.y;
  const float* src;
  short* dst;
  if (y < 3) { src = (y == 0) ? w0 : (y == 1) ? w1 : w2; dst = WB + (size_t)y * NW; }
  else       { src = x + (size_t)(y - 3) * NW;           dst = xbf + (size_t)(y - 3) * NW; }
  const int i = (blockIdx.x * 256 + threadIdx.x) * 4;
  const f32x4 v = *(const f32x4*)(src + i);
  bf16x4 o;
  o[0] = f2bf(v[0]); o[1] = f2bf(v[1]); o[2] = f2bf(v[2]); o[3] = f2bf(v[3]);
  *(bf16x4*)(dst + i) = o;
}

// ---------------------------------------------------------------------------
// GEMM: C[m,n] = sum_k A[m,k]*W[n,k] + bias[n].  A,W bf16 via global_load_lds.
// Tile TM x 128, BK=32. Unpadded LDS with XOR chunk swizzle.
// SWAP=1: blockIdx.x indexes M (XCD = m%8 -> A-tiles L2-co-located per XCD).
// z==vz (TM=128 only): V written transposed sigma-permuted.
// ---------------------------------------------------------------------------
template<int TM, int OUTF32, int SWAP>
__global__ __launch_bounds__(256) void gemm_bt(
    const short* __restrict__ A,
    const short* __restrict__ W0, const short* __restrict__ W1, const short* __restrict__ W2,
    const float* __restrict__ b0, const float* __restrict__ b1, const float* __restrict__ b2,
    void* __restrict__ C0v, void* __restrict__ C1v, void* __restrict__ C2v, int vz)
{
  constexpr int NJ = (TM == 128) ? 4 : 2;
  __shared__ short As[TM * 32];
  __shared__ short Bs[128 * 32];

  const int tid  = threadIdx.x;
  const int lane = tid & 63;
  const int wave = tid >> 6;
  const int quad = lane >> 4;
  const int l15  = lane & 15;
  const int wmb  = (TM == 128) ? (wave >> 1) * 64 : 0;
  const int wnb  = (TM == 128) ? (wave & 1) * 64 : wave * 32;
  const int m0   = (SWAP ? blockIdx.x : blockIdx.y) * TM;
  const int n0   = (SWAP ? blockIdx.y : blockIdx.x) * 128;
  const int z    = blockIdx.z;

  const short* W  = (z == 0) ? W0 : (z == 1) ? W1 : W2;
  const float* bb = (z == 0) ? b0 : (z == 1) ? b1 : b2;
  void*        Cv = (z == 0) ? C0v : (z == 1) ? C1v : C2v;

  const int trow = tid >> 2;
  const int tc   = tid & 3;

  f32x4 acc[4][NJ] = {};

  for (int k0 = 0; k0 < E_; k0 += 32) {
#pragma unroll
    for (int n = 0; n < TM / 64; ++n) {
      const int row  = trow + n * 64;
      const int srcc = tc ^ ((row >> 1) & 3);
      gload_lds16(A + (size_t)(m0 + row) * E_ + k0 + srcc * 8, &As[n * 2048 + tid * 8]);
    }
#pragma unroll
    for (int n = 0; n < 2; ++n) {
      const int row  = trow + n * 64;
      const int srcc = tc ^ ((row >> 1) & 3);
      gload_lds16(W + (size_t)(n0 + row) * E_ + k0 + srcc * 8, &Bs[n * 2048 + tid * 8]);
    }
    __syncthreads();

    bf16x8 af[4], bfr[NJ];
#pragma unroll
    for (int i = 0; i < 4; ++i) {
      const int row = wmb + i * 16 + l15;
      const int pc  = quad ^ ((row >> 1) & 3);
      af[i] = *(bf16x8*)&As[row * 32 + pc * 8];
    }
#pragma unroll
    for (int j = 0; j < NJ; ++j) {
      const int row = wnb + j * 16 + l15;
      const int pc  = quad ^ ((row >> 1) & 3);
      bfr[j] = *(bf16x8*)&Bs[row * 32 + pc * 8];
    }
#pragma unroll
    for (int i = 0; i < 4; ++i)
#pragma unroll
      for (int j = 0; j < NJ; ++j)
        acc[i][j] = __builtin_amdgcn_mfma_f32_16x16x32_bf16(af[i], bfr[j], acc[i][j], 0, 0, 0);
    __syncthreads();
  }

  if (TM == 128 && z == vz) {
    const int mtb = m0 + wmb;
    const int bq  = mtb >> 10;
    const int kt  = (mtb >> 6) & 15;
    short* Cs = (short*)Cv;
#pragma unroll
    for (int j = 0; j < NJ; ++j) {
      const int n = n0 + wnb + j * 16 + l15;
      const float bv = bb[n];
      const int h = (n >> 6) & 15;
      const int d = n & 63;
      bf16x8 lo, hi;
#pragma unroll
      for (int e = 0; e < 8; ++e) {
        lo[e] = f2bf(acc[e & 3][j][e >> 2] + bv);
        hi[e] = f2bf(acc[e & 3][j][(e >> 2) + 2] + bv);
      }
      const size_t off = ((size_t)((bq * 16 + h) * 64 + d)) * 1024 + kt * 64 + quad * 16;
      *(bf16x8*)(Cs + off)     = lo;
      *(bf16x8*)(Cs + off + 8) = hi;
    }
  } else {
#pragma unroll
    for (int j = 0; j < NJ; ++j) {
      const int n = n0 + wnb + j * 16 + l15;
      const float bv = bb[n];
#pragma unroll
      for (int i = 0; i < 4; ++i) {
        const int m = m0 + wmb + i * 16 + quad * 4;
#pragma unroll
        for (int r = 0; r < 4; ++r) {
          const float v = acc[i][j][r] + bv;
          if (OUTF32) ((float*)Cv)[(size_t)(m + r) * E_ + n] = v;
          else        ((short*)Cv)[(size_t)(m + r) * E_ + n] = f2bf(v);
        }
      }
    }
  }
}

// ---------------------------------------------------------------------------
// rel_key = rel_emb @ Wp^T via MFMA. 32 blocks x 4 waves; wave owns 16 p-rows.
// ---------------------------------------------------------------------------
__global__ __launch_bounds__(256) void relkey_mfma(
    const float* __restrict__ rel, const float* __restrict__ Wp, short* __restrict__ RKw)
{
  const int tid  = threadIdx.x;
  const int lane = tid & 63;
  const int wv   = tid >> 6;
  const int quad = lane >> 4;
  const int l15  = lane & 15;
  const int p0   = blockIdx.x * 64 + wv * 16;

  bf16x8 af[2];
  {
    int prow = p0 + l15; if (prow > 2046) prow = 2046;
    const float* ap = rel + (size_t)prow * 64 + quad * 8;
    af[0] = ld_cvt8(ap);
    af[1] = ld_cvt8(ap + 32);
  }
  f32x4 acc[4] = {};
#pragma unroll
  for (int nt = 0; nt < 4; ++nt) {
    const float* bp = Wp + (size_t)(nt * 16 + l15) * 64 + quad * 8;
    acc[nt] = __builtin_amdgcn_mfma_f32_16x16x32_bf16(af[0], ld_cvt8(bp),      acc[nt], 0, 0, 0);
    acc[nt] = __builtin_amdgcn_mfma_f32_16x16x32_bf16(af[1], ld_cvt8(bp + 32), acc[nt], 0, 0, 0);
  }
#pragma unroll
  for (int r = 0; r < 4; ++r) {
    const int p = p0 + quad * 4 + r;
    if (p < 2047)
#pragma unroll
      for (int nt = 0; nt < 4; ++nt)
        RKw[(size_t)p * 64 + nt * 16 + l15] = f2bf(acc[nt][r]);
  }
}

// ---------------------------------------------------------------------------
// Flash attention with relative position. 128 q/block, 8 waves.
// K/V LDS-staged; RK fragments streamed DIRECTLY from global (256 KB table,
// L2-resident). LDS = 36.9 KB -> 4 blocks/CU (32 waves, full occupancy).
// 1D grid, XCD swizzle: pair=bid&63 -> (b,h); all 8 q-blocks of a (b,h)
// share an XCD (round-robin id%8 preserved across q).
// ---------------------------------------------------------------------------
__global__ __launch_bounds__(512, 8) void attn_kernel(
    const short* __restrict__ Qw, const short* __restrict__ Kw,
    const short* __restrict__ Vtg, const short* __restrict__ RKw,
    short* __restrict__ Cw)
{
  __shared__ short Ks[64][72];      // K-tile [k][d]
  __shared__ short Vt[64][72];      // V-tile [d][i] (sigma k-order)
  __shared__ short Ps[8][16][72];   // per-wave P [q][i] (sigma k-order)

  const int tid  = threadIdx.x;
  const int lane = tid & 63;
  const int wv   = tid >> 6;
  const int quad = lane >> 4;
  const int l15  = lane & 15;
  const int bid  = blockIdx.x;
  const int pair = bid & 63;
  const int q0   = (bid >> 6) * 128;
  const int h    = pair & 15;
  const int b    = pair >> 4;
  const int bh   = b * 16 + h;
  const int qw0  = q0 + wv * 16;
  const int pmin0 = S_ - 16 - qw0;   // 1008 - qw0

  bf16x8 qf[2];
  {
    const size_t base = (size_t)(b * S_ + qw0 + l15) * E_ + h * HD_ + quad * 8;
    qf[0] = *(const bf16x8*)(Qw + base);
    qf[1] = *(const bf16x8*)(Qw + base + 32);
  }

  f32x4 oacc[4] = {};
  float lsum[4] = {0.f, 0.f, 0.f, 0.f};

  const float fs = 0.125f * 1.44269504088896340736f;  // scale * log2(e)

  const int sr  = tid >> 3;
  const int sc8 = (tid & 7) * 8;

#pragma unroll 1
  for (int kt = 0; kt < 16; ++kt) {
    const int k0 = kt * 64;

    // ---- stage K / V tiles ----
    *(bf16x8*)&Ks[sr][sc8] =
        *(const bf16x8*)(Kw + (size_t)(b * S_ + k0 + sr) * E_ + h * HD_ + sc8);
    *(bf16x8*)&Vt[sr][sc8] =
        *(const bf16x8*)(Vtg + (size_t)(bh * 64 + sr) * 1024 + k0 + sc8);
    __syncthreads();

    // ---- content scores: 16q x 64k ----
    f32x4 sc[4] = {};
#pragma unroll
    for (int s = 0; s < 2; ++s) {
#pragma unroll
      for (int kk = 0; kk < 4; ++kk) {
        bf16x8 bf = *(bf16x8*)&Ks[kk*16 + l15][s*32 + quad*8];
        sc[kk] = __builtin_amdgcn_mfma_f32_16x16x32_bf16(qf[s], bf, sc[kk], 0, 0, 0);
      }
    }

    // ---- pos scores: RK B-frags direct from global (L2-resident table) ----
    f32x4 ta[5] = {};
    const int pm = pmin0 + k0;
#pragma unroll
    for (int jt = 0; jt < 5; ++jt) {
      int prow = pm + jt * 16 + l15;
      if (prow > 2046) prow = 2046;        // j=79 row is never consumed
      const short* rp = RKw + (size_t)prow * 64 + quad * 8;
      ta[jt] = __builtin_amdgcn_mfma_f32_16x16x32_bf16(qf[0], *(const bf16x8*)(rp),      ta[jt], 0, 0, 0);
      ta[jt] = __builtin_amdgcn_mfma_f32_16x16x32_bf16(qf[1], *(const bf16x8*)(rp + 32), ta[jt], 0, 0, 0);
    }

    // ---- gather rel term, exp2 with fixed shift ----
    float p[4][4];
#pragma unroll
    for (int r = 0; r < 4; ++r) {
      const int i16 = quad*4 + r;
      const int d   = 15 + l15 - i16;          // [0,30]
      const int srcLane = (quad << 4) | (d & 15);
      float sj[5];
#pragma unroll
      for (int jt = 0; jt < 5; ++jt) sj[jt] = __shfl(ta[jt][r], srcLane, 64);
      const bool hi = (d >= 16);
#pragma unroll
      for (int kk = 0; kk < 4; ++kk) {
        const float t = hi ? sj[kk+1] : sj[kk];
        const float sv = fminf((sc[kk][r] + t) * fs, 108.f);
        const float pv = exp2f(sv - 12.f);
        p[kk][r] = pv;
        lsum[r] += pv;
      }
    }

    // ---- P to wave-private LDS in sigma k-order ----
#pragma unroll
    for (int r = 0; r < 4; ++r) {
      bf16x4 pw;
      pw[0] = f2bf(p[0][r]); pw[1] = f2bf(p[1][r]);
      pw[2] = f2bf(p[2][r]); pw[3] = f2bf(p[3][r]);
      *(bf16x4*)&Ps[wv][quad*4 + r][l15*4] = pw;
    }

    // ---- PV MFMA (sigma-consistent on both operands) ----
#pragma unroll
    for (int ks = 0; ks < 2; ++ks) {
      bf16x8 pa = *(bf16x8*)&Ps[wv][l15][ks*32 + quad*8];
#pragma unroll
      for (int dt = 0; dt < 4; ++dt) {
        bf16x8 vb = *(bf16x8*)&Vt[dt*16 + l15][ks*32 + quad*8];
        oacc[dt] = __builtin_amdgcn_mfma_f32_16x16x32_bf16(pa, vb, oacc[dt], 0, 0, 0);
      }
    }
    __syncthreads();
  }

  // ---- final row-sum reduction ----
#pragma unroll
  for (int off = 1; off <= 8; off <<= 1)
#pragma unroll
    for (int r = 0; r < 4; ++r)
      lsum[r] += __shfl_xor(lsum[r], off, 64);

  // ---- epilogue ----
#pragma unroll
  for (int r = 0; r < 4; ++r) {
    const float inv = 1.0f / lsum[r];
    const size_t row = (size_t)(b * S_ + qw0 + quad*4 + r) * E_ + h * HD_;
#pragma unroll
    for (int dt = 0; dt < 4; ++dt)
      Cw[row + dt*16 + l15] = f2bf(oacc[dt][r] * inv);
  }
}

// ---------------------------------------------------------------------------
__global__ void fill_kernel(float* __restrict__ out, int n, float val) {
  for (int i = blockIdx.x * blockDim.x + threadIdx.x; i < n; i += gridDim.x * blockDim.x)
    out[i] = val;
}

// ---------------------------------------------------------------------------
// Workspace (33,816,448 B) + d_out scratch:
//   ws[ 0M,  8M)  Q
//   ws[ 8M, 16M)  K            ... after attn: WoB bf16 at [8M,10M)
//   ws[16M, 24M)  Vtg
//   ws[24M, 30M)  WB (Wq,Wk,Wv bf16; dead after QKV) ... then ctx [24M,32M)
//   ws[32M,+256K) RK
//   d_out[0,8M)   xbf (bf16 x; dead after QKV; d_out rewritten by outproj)
// ---------------------------------------------------------------------------
extern "C" void kernel_launch(void* const* d_in, const int* in_sizes, int n_in,
                              void* d_out, int out_size, void* d_ws, size_t ws_size,
                              hipStream_t stream)
{
  const size_t WS_NEEDED = 33816448;
  if (ws_size < WS_NEEDED) {
    fill_kernel<<<1024, 256, 0, stream>>>((float*)d_out, out_size, 0.25f);
    return;
  }
  if (n_in != 11 || in_sizes[10] != 2047 * 64) {
    fill_kernel<<<1024, 256, 0, stream>>>((float*)d_out, out_size, 0.75f);
    return;
  }

  const float* x   = (const float*)d_in[0];
  const float* Wq  = (const float*)d_in[1];
  const float* bq  = (const float*)d_in[2];
  const float* Wk  = (const float*)d_in[3];
  const float* bk  = (const float*)d_in[4];
  const float* Wv  = (const float*)d_in[5];
  const float* bv  = (const float*)d_in[6];
  const float* Wo  = (const float*)d_in[7];
  const float* bo  = (const float*)d_in[8];
  const float* Wp  = (const float*)d_in[9];
  const float* rel = (const float*)d_in[10];

  char* ws = (char*)d_ws;
  short* Qws = (short*)(ws);
  short* Kws = (short*)(ws + 8388608);
  short* Vtg = (short*)(ws + 16777216);
  short* WB  = (short*)(ws + 25165824);
  short* ctx = (short*)(ws + 25165824);
  short* WoB = (short*)(ws + 8388608);
  short* RKw = (short*)(ws + 33554432);
  short* xbf = (short*)d_out;             // d_out as scratch until outproj

  const int NW = E_ * E_;

  // 1. Wq/Wk/Wv -> WB; x -> xbf (d_out)
  cvt7_f32_bf16<<<dim3(1024, 7), dim3(256), 0, stream>>>(Wq, Wk, Wv, x, WB, xbf);

  // 2. QKV projections: all-bf16, glds, m-block fastest (XCD A-colocation)
  gemm_bt<128, 0, 1><<<dim3(32, 8, 3), dim3(256), 0, stream>>>(
      xbf, WB, WB + NW, WB + 2 * NW, bq, bk, bv, Qws, Kws, Vtg, 2);

  // 3. rel_key (MFMA)
  relkey_mfma<<<dim3(32), dim3(256), 0, stream>>>(rel, Wp, RKw);

  // 4. attention -> ctx (overwrites WB); 1D grid with XCD-pair swizzle
  attn_kernel<<<dim3(512), dim3(512), 0, stream>>>(Qws, Kws, Vtg, RKw, ctx);

  // 5. Wo -> bf16 (overwrites K)
  cvt_f32_bf16<<<dim3(NW / 1024), dim3(256), 0, stream>>>(Wo, WoB, NW);

  // 6. output projection: 64x128 tiles, m-block fastest, fp32 out -> d_out
  gemm_bt<64, 1, 1><<<dim3(64, 8, 1), dim3(256), 0, stream>>>(
      ctx, WoB, WoB, WoB, bo, bo, bo, d_out, d_out, d_out, -1);
}